// Round 2
// baseline (2530.054 us; speedup 1.0000x reference)
//
#include <hip/hip_runtime.h>
#include <hip/hip_bf16.h>
#include <cstdint>

typedef __hip_bfloat16 bf16;

#define C_IN   64
#define C_HID  128
#define C_LAT  32
#define C_H    8
#define C_L    3
#define C_G    64

// Runtime input-dtype handling: the harness may hand us fp32 or bf16 tensors.
// flag==1 -> fp32, flag==0 -> bf16. Decided on-device by bit inspection.
__device__ inline float load_in(const void* p, size_t idx, int is_f32) {
    if (is_f32) return ((const float*)p)[idx];
    return __bfloat162float(((const bf16*)p)[idx]);
}

// Scan first 8192 half-words of W_embed. If data is fp32, the low half of each
// word is ~random mantissa bits -> ~47% decode to |bf16| >= 2^8 (exp >= 135).
// Real bf16 weights are |W| <~ 0.3 (exp <= 125) -> count == 0.
__global__ void detect_dtype(const unsigned short* __restrict__ W, int* __restrict__ flag) {
    __shared__ int cnt;
    if (threadIdx.x == 0) cnt = 0;
    __syncthreads();
    int local = 0;
    for (int i = threadIdx.x; i < 8192; i += 256) {
        int e = (W[i] >> 7) & 0xFF;
        if (e >= 135) local++;
    }
    atomicAdd(&cnt, local);
    __syncthreads();
    if (threadIdx.x == 0) *flag = (cnt > 64) ? 1 : 0;
}

// ---------- weight repack: [2,out,in,H] -> fp32 B [in*16, out], k = i*16 + trig*8 + h ----------
__global__ void repack_embed(const void* __restrict__ W, float* __restrict__ B, const int* __restrict__ flagp) {
    const int is_f32 = *flagp;
    int idx = blockIdx.x * blockDim.x + threadIdx.x;
    if (idx >= 2 * C_HID * C_IN * C_H) return;
    int h = idx & 7; int t = idx >> 3;
    int i = t & 63; t >>= 6;
    int o = t & 127; int trig = t >> 7;
    B[(i * 16 + trig * 8 + h) * C_HID + o] = load_in(W, idx, is_f32);
}

__global__ void repack_mp(const void* __restrict__ W, float* __restrict__ B, const int* __restrict__ flagp) {
    const int is_f32 = *flagp;
    int idx = blockIdx.x * blockDim.x + threadIdx.x;
    if (idx >= C_L * 2 * C_HID * C_HID * C_H) return;
    int h = idx & 7; int t = idx >> 3;
    int i = t & 127; t >>= 7;
    int o = t & 127; t >>= 7;
    int trig = t & 1; int l = t >> 1;
    B[((size_t)l * 2048 + i * 16 + trig * 8 + h) * C_HID + o] = load_in(W, idx, is_f32);
}

__global__ void repack_read(const void* __restrict__ W, float* __restrict__ B, const int* __restrict__ flagp) {
    const int is_f32 = *flagp;
    int idx = blockIdx.x * blockDim.x + threadIdx.x;
    if (idx >= 2 * C_LAT * C_HID * C_H) return;
    int h = idx & 7; int t = idx >> 3;
    int i = t & 127; t >>= 7;
    int o = t & 31; int trig = t >> 5;
    B[(i * 16 + trig * 8 + h) * C_LAT + o] = load_in(W, idx, is_f32);
}

// ---------- degree histogram over edges + self loops ----------
__global__ void deg_count(const int* __restrict__ col, int* __restrict__ deg, int E, int N) {
    int idx = blockIdx.x * blockDim.x + threadIdx.x;
    if (idx >= E + N) return;
    int c = (idx < E) ? col[idx] : (idx - E);
    atomicAdd(&deg[c], 1);
}

__global__ void dinv_kernel(const int* __restrict__ deg, float* __restrict__ dinv,
                            const int* __restrict__ batch, float* __restrict__ gcnt, int N) {
    int n = blockIdx.x * blockDim.x + threadIdx.x;
    if (n >= N) return;
    dinv[n] = rsqrtf((float)deg[n]);   // deg >= 1 (self loop)
    atomicAdd(&gcnt[batch[n]], 1.0f);
}

// ---------- single-block exclusive scan (rowptr) ----------
__global__ void scan_kernel(const int* __restrict__ deg, int* __restrict__ rowptr, int N) {
    __shared__ int sdata[1024];
    __shared__ int carry_s;
    if (threadIdx.x == 0) { carry_s = 0; rowptr[0] = 0; }
    __syncthreads();
    for (int base = 0; base < N; base += 1024) {
        int i = base + (int)threadIdx.x;
        int v = (i < N) ? deg[i] : 0;
        sdata[threadIdx.x] = v;
        __syncthreads();
        for (int off = 1; off < 1024; off <<= 1) {
            int t = (threadIdx.x >= (unsigned)off) ? sdata[threadIdx.x - off] : 0;
            __syncthreads();
            sdata[threadIdx.x] += t;
            __syncthreads();
        }
        int incl = sdata[threadIdx.x] + carry_s;
        if (i < N) rowptr[i + 1] = incl;
        __syncthreads();
        if (threadIdx.x == 1023) carry_s = incl;
        __syncthreads();
    }
}

__global__ void csr_fill(const int* __restrict__ row, const int* __restrict__ col,
                         const int* __restrict__ rowptr, int* __restrict__ cursor,
                         int* __restrict__ srcs, int E, int N) {
    int idx = blockIdx.x * blockDim.x + threadIdx.x;
    if (idx >= E + N) return;
    int r, c;
    if (idx < E) { r = row[idx]; c = col[idx]; } else { r = c = idx - E; }
    int pos = rowptr[c] + atomicAdd(&cursor[c], 1);
    srcs[pos] = r;
}

// ---------- fused Phi-generation SGEMM: Y[M,128] = Phi(X)[M, INF*16] x B[INF*16,128] ----------
// flagp == nullptr -> X is fp32 (internal buffer); else runtime flag decides.
template<int INF>
__global__ __launch_bounds__(256) void kan_gemm(const void* __restrict__ X, const float* __restrict__ B,
                                                float* __restrict__ Y, int M, const int* __restrict__ flagp) {
    __shared__ float As[16][128];
    __shared__ float Bs[16][128];
    const int is_f32 = flagp ? *flagp : 1;
    const int tid = threadIdx.x;
    const int tx = tid & 15, ty = tid >> 4;
    const int m0 = blockIdx.x * 128;
    float acc[8][8] = {};
    for (int i = 0; i < INF; ++i) {
        if (tid < 128) {
            int m = m0 + tid;
            float x = (m < M) ? load_in(X, (size_t)m * INF + i, is_f32) : 0.f;
            float s1, c1;
            __sincosf(x, &s1, &c1);
            As[0][tid] = c1; As[8][tid] = s1;
            float ck = c1, sk = s1;
#pragma unroll
            for (int h = 1; h < 8; ++h) {
                float cn = ck * c1 - sk * s1;   // cos((h+1)x)
                float sn = sk * c1 + ck * s1;   // sin((h+1)x)
                As[h][tid] = cn; As[8 + h][tid] = sn;
                ck = cn; sk = sn;
            }
        }
        const float4* Bg = (const float4*)(B + (size_t)i * 16 * 128);
        float4* BsV = (float4*)&Bs[0][0];
        BsV[tid]       = Bg[tid];
        BsV[tid + 256] = Bg[tid + 256];
        __syncthreads();
#pragma unroll
        for (int k = 0; k < 16; ++k) {
            float a[8], b[8];
            *(float4*)&a[0] = *(float4*)&As[k][ty * 8];
            *(float4*)&a[4] = *(float4*)&As[k][ty * 8 + 4];
            *(float4*)&b[0] = *(float4*)&Bs[k][tx * 8];
            *(float4*)&b[4] = *(float4*)&Bs[k][tx * 8 + 4];
#pragma unroll
            for (int r = 0; r < 8; ++r)
#pragma unroll
                for (int c = 0; c < 8; ++c)
                    acc[r][c] = fmaf(a[r], b[c], acc[r][c]);
        }
        __syncthreads();
    }
#pragma unroll
    for (int r = 0; r < 8; ++r) {
        int m = m0 + ty * 8 + r;
        if (m < M) {
            float4* Yv = (float4*)&Y[(size_t)m * 128 + tx * 8];
            Yv[0] = *(float4*)&acc[r][0];
            Yv[1] = *(float4*)&acc[r][4];
        }
    }
}

// ---------- CSR aggregation: one wave per destination node ----------
__global__ void aggregate(const float* __restrict__ Hin, float* __restrict__ Hout,
                          const int* __restrict__ rowptr, const int* __restrict__ srcs,
                          const float* __restrict__ dinv, int N) {
    int wave = (int)((blockIdx.x * blockDim.x + threadIdx.x) >> 6);
    int lane = threadIdx.x & 63;
    if (wave >= N) return;
    const float2* H2 = (const float2*)Hin;
    int beg = rowptr[wave], end = rowptr[wave + 1];
    float2 acc = {0.f, 0.f};
    for (int j = beg; j < end; ++j) {
        int s = srcs[j];
        float w = dinv[s];
        float2 hv = H2[(size_t)s * 64 + lane];
        acc.x = fmaf(w, hv.x, acc.x);
        acc.y = fmaf(w, hv.y, acc.y);
    }
    float dv = dinv[wave];
    acc.x *= dv; acc.y *= dv;
    ((float2*)Hout)[(size_t)wave * 64 + lane] = acc;
}

// ---------- mean pool ----------
__global__ void pool_sum(const float* __restrict__ H, const int* __restrict__ batch,
                         float* __restrict__ gsum, int N) {
    int idx = blockIdx.x * blockDim.x + threadIdx.x;
    if (idx >= N * C_HID) return;
    int n = idx >> 7, f = idx & 127;
    atomicAdd(&gsum[batch[n] * C_HID + f], H[idx]);
}

// ---------- readout: per-graph KAN to LAT outputs; store dtype per flag ----------
__global__ __launch_bounds__(256) void readout(const float* __restrict__ gsum, const float* __restrict__ gcnt,
                                               const float* __restrict__ B, void* __restrict__ out,
                                               const int* __restrict__ flagp) {
    __shared__ float phi[2048];
    __shared__ float part[8][32];
    const int is_f32 = *flagp;
    int g = blockIdx.x;
    int tid = threadIdx.x;
    if (tid < 128) {
        float cnt = fmaxf(gcnt[g], 1.0f);
        float x = gsum[g * C_HID + tid] / cnt;
        float s1, c1;
        __sincosf(x, &s1, &c1);
        phi[tid * 16 + 0] = c1; phi[tid * 16 + 8] = s1;
        float ck = c1, sk = s1;
#pragma unroll
        for (int h = 1; h < 8; ++h) {
            float cn = ck * c1 - sk * s1;
            float sn = sk * c1 + ck * s1;
            phi[tid * 16 + h] = cn; phi[tid * 16 + 8 + h] = sn;
            ck = cn; sk = sn;
        }
    }
    __syncthreads();
    int o = tid & 31, p = tid >> 5;
    float acc = 0.f;
    for (int k = p * 256; k < p * 256 + 256; ++k)
        acc = fmaf(phi[k], B[k * C_LAT + o], acc);
    part[p][o] = acc;
    __syncthreads();
    if (tid < 32) {
        float s = 0.f;
#pragma unroll
        for (int pp = 0; pp < 8; ++pp) s += part[pp][tid];
        if (is_f32) ((float*)out)[g * C_LAT + tid] = s;
        else        ((bf16*)out)[g * C_LAT + tid] = __float2bfloat16(s);
    }
}

extern "C" void kernel_launch(void* const* d_in, const int* in_sizes, int n_in,
                              void* d_out, int out_size, void* d_ws, size_t ws_size,
                              hipStream_t stream) {
    const void* features = d_in[0];
    const int*  edge     = (const int*)d_in[1];
    const int*  batch    = (const int*)d_in[2];
    const void* W_embed  = d_in[3];
    const void* W_mp     = d_in[4];
    const void* W_read   = d_in[5];

    const int N = in_sizes[0] / C_IN;
    const int E = in_sizes[1] / 2;
    const int* row = edge;
    const int* col = edge + E;

    char* ws = (char*)d_ws;
    auto alloc = [&](size_t bytes) { char* p = ws; ws += (bytes + 255) & ~(size_t)255; return p; };
    float* h_a    = (float*)alloc((size_t)N * C_HID * 4);
    float* h_b    = (float*)alloc((size_t)N * C_HID * 4);
    float* Bemb   = (float*)alloc((size_t)1024 * 128 * 4);
    float* Bmp    = (float*)alloc((size_t)3 * 2048 * 128 * 4);
    float* Brd    = (float*)alloc((size_t)2048 * 32 * 4);
    int*   deg    = (int*)alloc((size_t)N * 4);
    float* dinv   = (float*)alloc((size_t)N * 4);
    int*   rowptr = (int*)alloc((size_t)(N + 1) * 4);
    int*   cursor = (int*)alloc((size_t)N * 4);
    int*   srcs   = (int*)alloc((size_t)(E + N) * 4);
    float* gsum   = (float*)alloc((size_t)C_G * C_HID * 4);
    float* gcnt   = (float*)alloc((size_t)C_G * 4);
    int*   dflag  = (int*)alloc(256);

    hipMemsetAsync(deg, 0, (size_t)N * 4, stream);
    hipMemsetAsync(cursor, 0, (size_t)N * 4, stream);
    hipMemsetAsync(gsum, 0, (size_t)C_G * C_HID * 4, stream);
    hipMemsetAsync(gcnt, 0, (size_t)C_G * 4, stream);

    detect_dtype<<<1, 256, 0, stream>>>((const unsigned short*)W_embed, dflag);

    repack_embed<<<(2 * C_HID * C_IN * C_H + 255) / 256, 256, 0, stream>>>(W_embed, Bemb, dflag);
    repack_mp<<<(C_L * 2 * C_HID * C_HID * C_H + 255) / 256, 256, 0, stream>>>(W_mp, Bmp, dflag);
    repack_read<<<(2 * C_LAT * C_HID * C_H + 255) / 256, 256, 0, stream>>>(W_read, Brd, dflag);

    deg_count<<<(E + N + 255) / 256, 256, 0, stream>>>(col, deg, E, N);
    dinv_kernel<<<(N + 255) / 256, 256, 0, stream>>>(deg, dinv, batch, gcnt, N);
    scan_kernel<<<1, 1024, 0, stream>>>(deg, rowptr, N);
    csr_fill<<<(E + N + 255) / 256, 256, 0, stream>>>(row, col, rowptr, cursor, srcs, E, N);

    // embed: K = 64*16 = 1024
    kan_gemm<C_IN><<<(N + 127) / 128, 256, 0, stream>>>(features, Bemb, h_a, N, dflag);
    // 3 message-passing layers: K = 128*16 = 2048
    for (int l = 0; l < C_L; ++l) {
        kan_gemm<C_HID><<<(N + 127) / 128, 256, 0, stream>>>(h_a, Bmp + (size_t)l * 2048 * 128, h_b, N, nullptr);
        aggregate<<<((size_t)N * 64 + 255) / 256, 256, 0, stream>>>(h_b, h_a, rowptr, srcs, dinv, N);
    }

    pool_sum<<<((size_t)N * C_HID + 255) / 256, 256, 0, stream>>>(h_a, batch, gsum, N);
    readout<<<C_G, 256, 0, stream>>>(gsum, gcnt, Brd, d_out, dflag);
}

// Round 4
// 1627.382 us; speedup vs baseline: 1.5547x; 1.5547x over previous
//
#include <hip/hip_runtime.h>
#include <hip/hip_bf16.h>
#include <cstdint>

typedef __hip_bfloat16 bf16;
typedef _Float16 f16;
typedef f16 f16x8 __attribute__((ext_vector_type(8)));
typedef float f32x4 __attribute__((ext_vector_type(4)));

#define C_IN   64
#define C_HID  128
#define C_LAT  32
#define C_H    8
#define C_L    3
#define C_G    64

// Runtime input-dtype handling (harness may hand fp32 or bf16). flag==1 -> fp32.
__device__ inline float load_in(const void* p, size_t idx, int is_f32) {
    if (is_f32) return ((const float*)p)[idx];
    return __bfloat162float(((const bf16*)p)[idx]);
}

__global__ void detect_dtype(const unsigned short* __restrict__ W, int* __restrict__ flag) {
    __shared__ int cnt;
    if (threadIdx.x == 0) cnt = 0;
    __syncthreads();
    int local = 0;
    for (int i = threadIdx.x; i < 8192; i += 256) {
        int e = (W[i] >> 7) & 0xFF;
        if (e >= 135) local++;
    }
    atomicAdd(&cnt, local);
    __syncthreads();
    if (threadIdx.x == 0) *flag = (cnt > 64) ? 1 : 0;
}

// ---------- weight repack -> split fp16 (hi/lo) Bt[n][k], k = i*16 + trig*8 + h ----------
__device__ inline void split16(float v, f16& hi, f16& lo) {
    hi = (f16)v;
    lo = (f16)(v - (float)hi);
}

__global__ void repack_embed(const void* __restrict__ W, f16* __restrict__ Bh, f16* __restrict__ Bl,
                             const int* __restrict__ flagp) {
    const int is_f32 = *flagp;
    int idx = blockIdx.x * blockDim.x + threadIdx.x;
    if (idx >= 2 * C_HID * C_IN * C_H) return;
    int h = idx & 7; int t = idx >> 3;
    int i = t & 63; t >>= 6;
    int o = t & 127; int trig = t >> 7;
    f16 hi, lo; split16(load_in(W, idx, is_f32), hi, lo);
    int k = i * 16 + trig * 8 + h;
    Bh[o * 1024 + k] = hi;
    Bl[o * 1024 + k] = lo;
}

__global__ void repack_mp(const void* __restrict__ W, f16* __restrict__ Bh, f16* __restrict__ Bl,
                          const int* __restrict__ flagp) {
    const int is_f32 = *flagp;
    int idx = blockIdx.x * blockDim.x + threadIdx.x;
    if (idx >= C_L * 2 * C_HID * C_HID * C_H) return;
    int h = idx & 7; int t = idx >> 3;
    int i = t & 127; t >>= 7;
    int o = t & 127; t >>= 7;
    int trig = t & 1; int l = t >> 1;
    f16 hi, lo; split16(load_in(W, idx, is_f32), hi, lo);
    size_t k = (size_t)(l * 128 + o) * 2048 + i * 16 + trig * 8 + h;
    Bh[k] = hi;
    Bl[k] = lo;
}

// readout weights stay fp32 (tiny GEMM)
__global__ void repack_read(const void* __restrict__ W, float* __restrict__ B, const int* __restrict__ flagp) {
    const int is_f32 = *flagp;
    int idx = blockIdx.x * blockDim.x + threadIdx.x;
    if (idx >= 2 * C_LAT * C_HID * C_H) return;
    int h = idx & 7; int t = idx >> 3;
    int i = t & 127; t >>= 7;
    int o = t & 31; int trig = t >> 5;
    B[(i * 16 + trig * 8 + h) * C_LAT + o] = load_in(W, idx, is_f32);
}

// ---------- graph prep ----------
__global__ void deg_count(const int* __restrict__ col, int* __restrict__ deg, int E, int N) {
    int idx = blockIdx.x * blockDim.x + threadIdx.x;
    if (idx >= E + N) return;
    int c = (idx < E) ? col[idx] : (idx - E);
    atomicAdd(&deg[c], 1);
}

__global__ void dinv_kernel(const int* __restrict__ deg, float* __restrict__ dinv,
                            const int* __restrict__ batch, float* __restrict__ gcnt, int N) {
    int n = blockIdx.x * blockDim.x + threadIdx.x;
    if (n >= N) return;
    dinv[n] = rsqrtf((float)deg[n]);   // deg >= 1 (self loop)
    atomicAdd(&gcnt[batch[n]], 1.0f);
}

__global__ void scan_kernel(const int* __restrict__ deg, int* __restrict__ rowptr, int N) {
    __shared__ int sdata[1024];
    __shared__ int carry_s;
    if (threadIdx.x == 0) { carry_s = 0; rowptr[0] = 0; }
    __syncthreads();
    for (int base = 0; base < N; base += 1024) {
        int i = base + (int)threadIdx.x;
        int v = (i < N) ? deg[i] : 0;
        sdata[threadIdx.x] = v;
        __syncthreads();
        for (int off = 1; off < 1024; off <<= 1) {
            int t = (threadIdx.x >= (unsigned)off) ? sdata[threadIdx.x - off] : 0;
            __syncthreads();
            sdata[threadIdx.x] += t;
            __syncthreads();
        }
        int incl = sdata[threadIdx.x] + carry_s;
        if (i < N) rowptr[i + 1] = incl;
        __syncthreads();
        if (threadIdx.x == 1023) carry_s = incl;
        __syncthreads();
    }
}

__global__ void csr_fill(const int* __restrict__ row, const int* __restrict__ col,
                         const int* __restrict__ rowptr, int* __restrict__ cursor,
                         int* __restrict__ srcs, int E, int N) {
    int idx = blockIdx.x * blockDim.x + threadIdx.x;
    if (idx >= E + N) return;
    int r, c;
    if (idx < E) { r = row[idx]; c = col[idx]; } else { r = c = idx - E; }
    int pos = rowptr[c] + atomicAdd(&cursor[c], 1);
    srcs[pos] = r;
}

// ---------- Phi split-fp16 generation: 16 values (cos(kx) k=1..8, sin(kx) k=1..8) ----------
#define SR 40   // LDS row stride in f16 (32 data + 8 pad); 80 B: 16B-aligned, non-pow2 banks

__device__ inline void phi_write_split(f16* __restrict__ Ah, f16* __restrict__ Al,
                                       int row, int f, float x) {
    float c[8], s[8];
    __sincosf(x, &s[0], &c[0]);
#pragma unroll
    for (int h = 1; h < 8; ++h) {
        c[h] = c[h-1] * c[0] - s[h-1] * s[0];
        s[h] = s[h-1] * c[0] + c[h-1] * s[0];
    }
    f16x8 ch, cl, sh, sl;
#pragma unroll
    for (int h = 0; h < 8; ++h) {
        f16 hi, lo;
        split16(c[h], hi, lo); ch[h] = hi; cl[h] = lo;
        split16(s[h], hi, lo); sh[h] = hi; sl[h] = lo;
    }
    *(f16x8*)&Ah[row * SR + f * 16]     = ch;
    *(f16x8*)&Ah[row * SR + f * 16 + 8] = sh;
    *(f16x8*)&Al[row * SR + f * 16]     = cl;
    *(f16x8*)&Al[row * SR + f * 16 + 8] = sl;
}

// ---------- split-fp16 MFMA fused-Phi GEMM: Y[M,128] = Phi(X)[M, INF*16] x Bt^T ----------
// Block: 64 M-rows x 128 N-cols, 4 waves side by side (wave tile 64x32, acc 4x2).
// K chunked by 32 (2 input features). acc = Ah*Bh + Ah*Bl + Al*Bh (fp32-accurate).
template<int INF>
__global__ __launch_bounds__(256, 3) void kan_gemm_mfma(const void* __restrict__ X,
                                                        const f16* __restrict__ Bth, const f16* __restrict__ Btl,
                                                        float* __restrict__ Y, int M, const int* __restrict__ flagp) {
    constexpr int K = INF * 16;
    constexpr int NCH = INF / 2;     // chunks of K=32
    __shared__ f16 Ah[64 * SR], Al[64 * SR], Bh[128 * SR], Bl[128 * SR];
    const int is_f32 = flagp ? *flagp : 1;
    const int tid  = threadIdx.x;
    const int m0   = blockIdx.x * 64;
    const int w    = tid >> 6, lane = tid & 63;
    const int quad = lane >> 4, l16 = lane & 15;

    // Phi-gen: threads 0..127 handle (row = tid&63, feature slot pf = tid>>6)
    const int prow = tid & 63;
    const int pf   = (tid >> 6) & 1;
    const bool pact = tid < 128;
    const int gm   = m0 + prow;
    // B staging: 2 threads per row, 16 k-elems each
    const int br = tid >> 1, bhs = tid & 1;

    f32x4 acc[4][2] = {};

    float xv = 0.f;
    if (pact && gm < M) xv = load_in(X, (size_t)gm * INF + pf, is_f32);

    for (int c = 0; c < NCH; ++c) {
        float xn = 0.f;
        if (c + 1 < NCH && pact && gm < M)
            xn = load_in(X, (size_t)gm * INF + (c + 1) * 2 + pf, is_f32);

        // B stage loads (L2-resident weights)
        const f16* gbh = Bth + (size_t)br * K + c * 32 + bhs * 16;
        const f16* gbl = Btl + (size_t)br * K + c * 32 + bhs * 16;
        f16x8 b0 = ((const f16x8*)gbh)[0];
        f16x8 b1 = ((const f16x8*)gbh)[1];
        f16x8 b2 = ((const f16x8*)gbl)[0];
        f16x8 b3 = ((const f16x8*)gbl)[1];

        // Phi for this chunk's 2 features (VALU overlaps the B loads)
        if (pact) phi_write_split(Ah, Al, prow, pf, xv);

        f16* dh = &Bh[br * SR + bhs * 16];
        f16* dl = &Bl[br * SR + bhs * 16];
        ((f16x8*)dh)[0] = b0; ((f16x8*)dh)[1] = b1;
        ((f16x8*)dl)[0] = b2; ((f16x8*)dl)[1] = b3;
        __syncthreads();

        f16x8 ah[4], al[4], bhf[2], blf[2];
#pragma unroll
        for (int mt = 0; mt < 4; ++mt) {
            ah[mt] = *(const f16x8*)&Ah[(mt * 16 + l16) * SR + quad * 8];
            al[mt] = *(const f16x8*)&Al[(mt * 16 + l16) * SR + quad * 8];
        }
#pragma unroll
        for (int nt = 0; nt < 2; ++nt) {
            bhf[nt] = *(const f16x8*)&Bh[(w * 32 + nt * 16 + l16) * SR + quad * 8];
            blf[nt] = *(const f16x8*)&Bl[(w * 32 + nt * 16 + l16) * SR + quad * 8];
        }
#pragma unroll
        for (int mt = 0; mt < 4; ++mt)
#pragma unroll
            for (int nt = 0; nt < 2; ++nt) {
                acc[mt][nt] = __builtin_amdgcn_mfma_f32_16x16x32_f16(ah[mt], bhf[nt], acc[mt][nt], 0, 0, 0);
                acc[mt][nt] = __builtin_amdgcn_mfma_f32_16x16x32_f16(ah[mt], blf[nt], acc[mt][nt], 0, 0, 0);
                acc[mt][nt] = __builtin_amdgcn_mfma_f32_16x16x32_f16(al[mt], bhf[nt], acc[mt][nt], 0, 0, 0);
            }
        __syncthreads();
        xv = xn;
    }

    // Store: C/D layout col=lane&15, row=quad*4+reg
#pragma unroll
    for (int mt = 0; mt < 4; ++mt) {
        int rbase = m0 + mt * 16 + quad * 4;
#pragma unroll
        for (int nt = 0; nt < 2; ++nt) {
            int cn = w * 32 + nt * 16 + l16;
#pragma unroll
            for (int r = 0; r < 4; ++r) {
                int m = rbase + r;
                if (m < M) Y[(size_t)m * 128 + cn] = acc[mt][nt][r];
            }
        }
    }
}

// ---------- CSR aggregation: one wave per destination node (fp32) ----------
__global__ void aggregate(const float* __restrict__ Hin, float* __restrict__ Hout,
                          const int* __restrict__ rowptr, const int* __restrict__ srcs,
                          const float* __restrict__ dinv, int N) {
    int wave = (int)((blockIdx.x * blockDim.x + threadIdx.x) >> 6);
    int lane = threadIdx.x & 63;
    if (wave >= N) return;
    const float2* H2 = (const float2*)Hin;
    int beg = rowptr[wave], end = rowptr[wave + 1];
    float2 acc = {0.f, 0.f};
    for (int j = beg; j < end; ++j) {
        int s = srcs[j];
        float w = dinv[s];
        float2 hv = H2[(size_t)s * 64 + lane];
        acc.x = fmaf(w, hv.x, acc.x);
        acc.y = fmaf(w, hv.y, acc.y);
    }
    float dv = dinv[wave];
    acc.x *= dv; acc.y *= dv;
    ((float2*)Hout)[(size_t)wave * 64 + lane] = acc;
}

// ---------- mean pool ----------
__global__ void pool_sum(const float* __restrict__ H, const int* __restrict__ batch,
                         float* __restrict__ gsum, int N) {
    int idx = blockIdx.x * blockDim.x + threadIdx.x;
    if (idx >= N * C_HID) return;
    int n = idx >> 7, f = idx & 127;
    atomicAdd(&gsum[batch[n] * C_HID + f], H[idx]);
}

// ---------- readout ----------
__global__ __launch_bounds__(256) void readout(const float* __restrict__ gsum, const float* __restrict__ gcnt,
                                               const float* __restrict__ B, void* __restrict__ out,
                                               const int* __restrict__ flagp) {
    __shared__ float phi[2048];
    __shared__ float part[8][32];
    const int is_f32 = *flagp;
    int g = blockIdx.x;
    int tid = threadIdx.x;
    if (tid < 128) {
        float cnt = fmaxf(gcnt[g], 1.0f);
        float x = gsum[g * C_HID + tid] / cnt;
        float s1, c1;
        __sincosf(x, &s1, &c1);
        phi[tid * 16 + 0] = c1; phi[tid * 16 + 8] = s1;
        float ck = c1, sk = s1;
#pragma unroll
        for (int h = 1; h < 8; ++h) {
            float cn = ck * c1 - sk * s1;
            float sn = sk * c1 + ck * s1;
            phi[tid * 16 + h] = cn; phi[tid * 16 + 8 + h] = sn;
            ck = cn; sk = sn;
        }
    }
    __syncthreads();
    int o = tid & 31, p = tid >> 5;
    float acc = 0.f;
    for (int k = p * 256; k < p * 256 + 256; ++k)
        acc = fmaf(phi[k], B[k * C_LAT + o], acc);
    part[p][o] = acc;
    __syncthreads();
    if (tid < 32) {
        float s = 0.f;
#pragma unroll
        for (int pp = 0; pp < 8; ++pp) s += part[pp][tid];
        if (is_f32) ((float*)out)[g * C_LAT + tid] = s;
        else        ((bf16*)out)[g * C_LAT + tid] = __float2bfloat16(s);
    }
}

extern "C" void kernel_launch(void* const* d_in, const int* in_sizes, int n_in,
                              void* d_out, int out_size, void* d_ws, size_t ws_size,
                              hipStream_t stream) {
    const void* features = d_in[0];
    const int*  edge     = (const int*)d_in[1];
    const int*  batch    = (const int*)d_in[2];
    const void* W_embed  = d_in[3];
    const void* W_mp     = d_in[4];
    const void* W_read   = d_in[5];

    const int N = in_sizes[0] / C_IN;
    const int E = in_sizes[1] / 2;
    const int* row = edge;
    const int* col = edge + E;

    char* ws = (char*)d_ws;
    auto alloc = [&](size_t bytes) { char* p = ws; ws += (bytes + 255) & ~(size_t)255; return p; };
    float* h_a    = (float*)alloc((size_t)N * C_HID * 4);
    float* h_b    = (float*)alloc((size_t)N * C_HID * 4);
    f16*   BteH   = (f16*)alloc((size_t)C_HID * 1024 * 2);
    f16*   BteL   = (f16*)alloc((size_t)C_HID * 1024 * 2);
    f16*   BtmpH  = (f16*)alloc((size_t)C_L * C_HID * 2048 * 2);
    f16*   BtmpL  = (f16*)alloc((size_t)C_L * C_HID * 2048 * 2);
    float* Brd    = (float*)alloc((size_t)2048 * C_LAT * 4);
    int*   deg    = (int*)alloc((size_t)N * 4);
    float* dinv   = (float*)alloc((size_t)N * 4);
    int*   rowptr = (int*)alloc((size_t)(N + 1) * 4);
    int*   cursor = (int*)alloc((size_t)N * 4);
    int*   srcs   = (int*)alloc((size_t)(E + N) * 4);
    float* gsum   = (float*)alloc((size_t)C_G * C_HID * 4);
    float* gcnt   = (float*)alloc((size_t)C_G * 4);
    int*   dflag  = (int*)alloc(256);

    hipMemsetAsync(deg, 0, (size_t)N * 4, stream);
    hipMemsetAsync(cursor, 0, (size_t)N * 4, stream);
    hipMemsetAsync(gsum, 0, (size_t)C_G * C_HID * 4, stream);
    hipMemsetAsync(gcnt, 0, (size_t)C_G * 4, stream);

    detect_dtype<<<1, 256, 0, stream>>>((const unsigned short*)W_embed, dflag);

    repack_embed<<<(2 * C_HID * C_IN * C_H + 255) / 256, 256, 0, stream>>>(W_embed, BteH, BteL, dflag);
    repack_mp<<<(C_L * 2 * C_HID * C_HID * C_H + 255) / 256, 256, 0, stream>>>(W_mp, BtmpH, BtmpL, dflag);
    repack_read<<<(2 * C_LAT * C_HID * C_H + 255) / 256, 256, 0, stream>>>(W_read, Brd, dflag);

    deg_count<<<(E + N + 255) / 256, 256, 0, stream>>>(col, deg, E, N);
    dinv_kernel<<<(N + 255) / 256, 256, 0, stream>>>(deg, dinv, batch, gcnt, N);
    scan_kernel<<<1, 1024, 0, stream>>>(deg, rowptr, N);
    csr_fill<<<(E + N + 255) / 256, 256, 0, stream>>>(row, col, rowptr, cursor, srcs, E, N);

    const int gemm_grid = (N + 63) / 64;
    // embed: K = 64*16 = 1024
    kan_gemm_mfma<C_IN><<<gemm_grid, 256, 0, stream>>>(features, BteH, BteL, h_a, N, dflag);
    // 3 message-passing layers: K = 128*16 = 2048
    for (int l = 0; l < C_L; ++l) {
        kan_gemm_mfma<C_HID><<<gemm_grid, 256, 0, stream>>>(h_a, BtmpH + (size_t)l * C_HID * 2048,
                                                            BtmpL + (size_t)l * C_HID * 2048, h_b, N, nullptr);
        aggregate<<<((size_t)N * 64 + 255) / 256, 256, 0, stream>>>(h_b, h_a, rowptr, srcs, dinv, N);
    }

    pool_sum<<<((size_t)N * C_HID + 255) / 256, 256, 0, stream>>>(h_a, batch, gsum, N);
    readout<<<C_G, 256, 0, stream>>>(gsum, gcnt, Brd, d_out, dflag);
}

// Round 5
// 1266.359 us; speedup vs baseline: 1.9979x; 1.2851x over previous
//
#include <hip/hip_runtime.h>
#include <hip/hip_bf16.h>
#include <cstdint>

typedef __hip_bfloat16 bf16;
typedef _Float16 f16;
typedef f16 f16x8 __attribute__((ext_vector_type(8)));
typedef float f32x4 __attribute__((ext_vector_type(4)));

#define C_IN   64
#define C_HID  128
#define C_LAT  32
#define C_H    8
#define C_L    3
#define C_G    64

// Runtime input-dtype handling (harness may hand fp32 or bf16). flag==1 -> fp32.
__device__ inline float load_in(const void* p, size_t idx, int is_f32) {
    if (is_f32) return ((const float*)p)[idx];
    return __bfloat162float(((const bf16*)p)[idx]);
}

__global__ void detect_dtype(const unsigned short* __restrict__ W, int* __restrict__ flag) {
    __shared__ int cnt;
    if (threadIdx.x == 0) cnt = 0;
    __syncthreads();
    int local = 0;
    for (int i = threadIdx.x; i < 8192; i += 256) {
        int e = (W[i] >> 7) & 0xFF;
        if (e >= 135) local++;
    }
    atomicAdd(&cnt, local);
    __syncthreads();
    if (threadIdx.x == 0) *flag = (cnt > 64) ? 1 : 0;
}

// ---------- weight repack -> split fp16 (hi/lo) Bt[n][k], k = i*16 + trig*8 + h ----------
__device__ inline void split16(float v, f16& hi, f16& lo) {
    hi = (f16)v;
    lo = (f16)(v - (float)hi);
}

__global__ void repack_embed(const void* __restrict__ W, f16* __restrict__ Bh, f16* __restrict__ Bl,
                             const int* __restrict__ flagp) {
    const int is_f32 = *flagp;
    int idx = blockIdx.x * blockDim.x + threadIdx.x;
    if (idx >= 2 * C_HID * C_IN * C_H) return;
    int h = idx & 7; int t = idx >> 3;
    int i = t & 63; t >>= 6;
    int o = t & 127; int trig = t >> 7;
    f16 hi, lo; split16(load_in(W, idx, is_f32), hi, lo);
    int k = i * 16 + trig * 8 + h;
    Bh[o * 1024 + k] = hi;
    Bl[o * 1024 + k] = lo;
}

__global__ void repack_mp(const void* __restrict__ W, f16* __restrict__ Bh, f16* __restrict__ Bl,
                          const int* __restrict__ flagp) {
    const int is_f32 = *flagp;
    int idx = blockIdx.x * blockDim.x + threadIdx.x;
    if (idx >= C_L * 2 * C_HID * C_HID * C_H) return;
    int h = idx & 7; int t = idx >> 3;
    int i = t & 127; t >>= 7;
    int o = t & 127; t >>= 7;
    int trig = t & 1; int l = t >> 1;
    f16 hi, lo; split16(load_in(W, idx, is_f32), hi, lo);
    size_t k = (size_t)(l * 128 + o) * 2048 + i * 16 + trig * 8 + h;
    Bh[k] = hi;
    Bl[k] = lo;
}

// readout weights stay fp32 (tiny GEMM)
__global__ void repack_read(const void* __restrict__ W, float* __restrict__ B, const int* __restrict__ flagp) {
    const int is_f32 = *flagp;
    int idx = blockIdx.x * blockDim.x + threadIdx.x;
    if (idx >= 2 * C_LAT * C_HID * C_H) return;
    int h = idx & 7; int t = idx >> 3;
    int i = t & 127; t >>= 7;
    int o = t & 31; int trig = t >> 5;
    B[(i * 16 + trig * 8 + h) * C_LAT + o] = load_in(W, idx, is_f32);
}

// ---------- graph prep ----------
__global__ void deg_count(const int* __restrict__ col, int* __restrict__ deg, int E, int N) {
    int idx = blockIdx.x * blockDim.x + threadIdx.x;
    if (idx >= E + N) return;
    int c = (idx < E) ? col[idx] : (idx - E);
    atomicAdd(&deg[c], 1);
}

__global__ void dinv_kernel(const int* __restrict__ deg, float* __restrict__ dinv, int N) {
    int n = blockIdx.x * blockDim.x + threadIdx.x;
    if (n >= N) return;
    dinv[n] = rsqrtf((float)deg[n]);   // deg >= 1 (self loop)
}

// batch is sorted: gstart[g] = lower_bound(batch, g), g = 0..G (gstart[G] = N)
__global__ void graph_bounds(const int* __restrict__ batch, int* __restrict__ gstart, int N) {
    int g = threadIdx.x;
    if (g > C_G) return;
    int lo = 0, hi = N;
    while (lo < hi) {
        int mid = (lo + hi) >> 1;
        if (batch[mid] < g) lo = mid + 1; else hi = mid;
    }
    gstart[g] = lo;
}

// ---------- hierarchical exclusive scan of deg -> rowptr ----------
__global__ void scan1(const int* __restrict__ deg, int* __restrict__ rowptr,
                      int* __restrict__ bsum, int N) {
    __shared__ int sdata[1024];
    int i = blockIdx.x * 1024 + threadIdx.x;
    int v = (i < N) ? deg[i] : 0;
    sdata[threadIdx.x] = v;
    __syncthreads();
    for (int off = 1; off < 1024; off <<= 1) {
        int t = (threadIdx.x >= (unsigned)off) ? sdata[threadIdx.x - off] : 0;
        __syncthreads();
        sdata[threadIdx.x] += t;
        __syncthreads();
    }
    if (i < N) rowptr[i + 1] = sdata[threadIdx.x];
    if (threadIdx.x == 1023) bsum[blockIdx.x] = sdata[1023];
}

__global__ void scan2(int* __restrict__ bsum, int nb) {
    if (threadIdx.x == 0) {
        int acc = 0;
        for (int i = 0; i < nb; ++i) { int t = bsum[i]; bsum[i] = acc; acc += t; }
    }
}

__global__ void scan3(int* __restrict__ rowptr, const int* __restrict__ bsum, int N) {
    int i = blockIdx.x * 1024 + threadIdx.x;
    if (i < N) rowptr[i + 1] += bsum[blockIdx.x];
    if (i == 0) rowptr[0] = 0;
}

__global__ void csr_fill(const int* __restrict__ row, const int* __restrict__ col,
                         const int* __restrict__ rowptr, int* __restrict__ cursor,
                         int* __restrict__ srcs, int E, int N) {
    int idx = blockIdx.x * blockDim.x + threadIdx.x;
    if (idx >= E + N) return;
    int r, c;
    if (idx < E) { r = row[idx]; c = col[idx]; } else { r = c = idx - E; }
    int pos = rowptr[c] + atomicAdd(&cursor[c], 1);
    srcs[pos] = r;
}

// ---------- Phi split-fp16 generation: 16 values (cos(kx) k=1..8, sin(kx) k=1..8) ----------
#define SR 40   // LDS row stride in f16 (32 data + 8 pad); 80 B: 16B-aligned, non-pow2 banks

__device__ inline void phi_write_split(f16* __restrict__ Ah, f16* __restrict__ Al,
                                       int row, int f, float x) {
    float c[8], s[8];
    __sincosf(x, &s[0], &c[0]);
#pragma unroll
    for (int h = 1; h < 8; ++h) {
        c[h] = c[h-1] * c[0] - s[h-1] * s[0];
        s[h] = s[h-1] * c[0] + c[h-1] * s[0];
    }
    f16x8 ch, cl, sh, sl;
#pragma unroll
    for (int h = 0; h < 8; ++h) {
        f16 hi, lo;
        split16(c[h], hi, lo); ch[h] = hi; cl[h] = lo;
        split16(s[h], hi, lo); sh[h] = hi; sl[h] = lo;
    }
    *(f16x8*)&Ah[row * SR + f * 16]     = ch;
    *(f16x8*)&Ah[row * SR + f * 16 + 8] = sh;
    *(f16x8*)&Al[row * SR + f * 16]     = cl;
    *(f16x8*)&Al[row * SR + f * 16 + 8] = sl;
}

// ---------- split-fp16 MFMA fused-Phi GEMM: Y[M,128] = Phi(X)[M, INF*16] x Bt^T ----------
// Block: 64 M-rows x 128 N-cols, 4 waves side by side (wave tile 64x32, acc 4x2).
// K chunked by 32 (2 input features). acc = Ah*Bh + Ah*Bl + Al*Bh (fp32-accurate).
template<int INF>
__global__ __launch_bounds__(256, 3) void kan_gemm_mfma(const void* __restrict__ X,
                                                        const f16* __restrict__ Bth, const f16* __restrict__ Btl,
                                                        float* __restrict__ Y, int M, const int* __restrict__ flagp) {
    constexpr int K = INF * 16;
    constexpr int NCH = INF / 2;     // chunks of K=32
    __shared__ f16 Ah[64 * SR], Al[64 * SR], Bh[128 * SR], Bl[128 * SR];
    const int is_f32 = flagp ? *flagp : 1;
    const int tid  = threadIdx.x;
    const int m0   = blockIdx.x * 64;
    const int w    = tid >> 6, lane = tid & 63;
    const int quad = lane >> 4, l16 = lane & 15;

    const int prow = tid & 63;
    const int pf   = (tid >> 6) & 1;
    const bool pact = tid < 128;
    const int gm   = m0 + prow;
    const int br = tid >> 1, bhs = tid & 1;

    f32x4 acc[4][2] = {};

    float xv = 0.f;
    if (pact && gm < M) xv = load_in(X, (size_t)gm * INF + pf, is_f32);

    for (int c = 0; c < NCH; ++c) {
        float xn = 0.f;
        if (c + 1 < NCH && pact && gm < M)
            xn = load_in(X, (size_t)gm * INF + (c + 1) * 2 + pf, is_f32);

        const f16* gbh = Bth + (size_t)br * K + c * 32 + bhs * 16;
        const f16* gbl = Btl + (size_t)br * K + c * 32 + bhs * 16;
        f16x8 b0 = ((const f16x8*)gbh)[0];
        f16x8 b1 = ((const f16x8*)gbh)[1];
        f16x8 b2 = ((const f16x8*)gbl)[0];
        f16x8 b3 = ((const f16x8*)gbl)[1];

        if (pact) phi_write_split(Ah, Al, prow, pf, xv);

        f16* dh = &Bh[br * SR + bhs * 16];
        f16* dl = &Bl[br * SR + bhs * 16];
        ((f16x8*)dh)[0] = b0; ((f16x8*)dh)[1] = b1;
        ((f16x8*)dl)[0] = b2; ((f16x8*)dl)[1] = b3;
        __syncthreads();

        f16x8 ah[4], al[4], bhf[2], blf[2];
#pragma unroll
        for (int mt = 0; mt < 4; ++mt) {
            ah[mt] = *(const f16x8*)&Ah[(mt * 16 + l16) * SR + quad * 8];
            al[mt] = *(const f16x8*)&Al[(mt * 16 + l16) * SR + quad * 8];
        }
#pragma unroll
        for (int nt = 0; nt < 2; ++nt) {
            bhf[nt] = *(const f16x8*)&Bh[(w * 32 + nt * 16 + l16) * SR + quad * 8];
            blf[nt] = *(const f16x8*)&Bl[(w * 32 + nt * 16 + l16) * SR + quad * 8];
        }
#pragma unroll
        for (int mt = 0; mt < 4; ++mt)
#pragma unroll
            for (int nt = 0; nt < 2; ++nt) {
                acc[mt][nt] = __builtin_amdgcn_mfma_f32_16x16x32_f16(ah[mt], bhf[nt], acc[mt][nt], 0, 0, 0);
                acc[mt][nt] = __builtin_amdgcn_mfma_f32_16x16x32_f16(ah[mt], blf[nt], acc[mt][nt], 0, 0, 0);
                acc[mt][nt] = __builtin_amdgcn_mfma_f32_16x16x32_f16(al[mt], bhf[nt], acc[mt][nt], 0, 0, 0);
            }
        __syncthreads();
        xv = xn;
    }

#pragma unroll
    for (int mt = 0; mt < 4; ++mt) {
        int rbase = m0 + mt * 16 + quad * 4;
#pragma unroll
        for (int nt = 0; nt < 2; ++nt) {
            int cn = w * 32 + nt * 16 + l16;
#pragma unroll
            for (int r = 0; r < 4; ++r) {
                int m = rbase + r;
                if (m < M) Y[(size_t)m * 128 + cn] = acc[mt][nt][r];
            }
        }
    }
}

// ---------- CSR aggregation: one wave per destination node (fp32) ----------
__global__ void aggregate(const float* __restrict__ Hin, float* __restrict__ Hout,
                          const int* __restrict__ rowptr, const int* __restrict__ srcs,
                          const float* __restrict__ dinv, int N) {
    int wave = (int)((blockIdx.x * blockDim.x + threadIdx.x) >> 6);
    int lane = threadIdx.x & 63;
    if (wave >= N) return;
    const float2* H2 = (const float2*)Hin;
    int beg = rowptr[wave], end = rowptr[wave + 1];
    float2 acc = {0.f, 0.f};
    for (int j = beg; j < end; ++j) {
        int s = srcs[j];
        float w = dinv[s];
        float2 hv = H2[(size_t)s * 64 + lane];
        acc.x = fmaf(w, hv.x, acc.x);
        acc.y = fmaf(w, hv.y, acc.y);
    }
    float dv = dinv[wave];
    acc.x *= dv; acc.y *= dv;
    ((float2*)Hout)[(size_t)wave * 64 + lane] = acc;
}

// ---------- fused mean-pool + readout: block g sums rows [gstart[g], gstart[g+1]) ----------
__global__ __launch_bounds__(256) void pool_readout(const float* __restrict__ H, const int* __restrict__ gstart,
                                                    const float* __restrict__ B, void* __restrict__ out,
                                                    const int* __restrict__ flagp) {
    __shared__ float phi[2048];
    __shared__ float red[256];
    __shared__ float part[8][32];
    const int is_f32 = *flagp;
    int g = blockIdx.x;
    int tid = threadIdx.x;
    int s0 = gstart[g], e0 = gstart[g + 1];
    int f = tid & 127, half = tid >> 7;
    float sum = 0.f;
    for (int n = s0 + half; n < e0; n += 2)
        sum += H[(size_t)n * C_HID + f];
    red[tid] = sum;
    __syncthreads();
    if (tid < 128) {
        float cnt = fmaxf((float)(e0 - s0), 1.0f);
        float x = (red[tid] + red[tid + 128]) / cnt;
        float s1, c1;
        __sincosf(x, &s1, &c1);
        phi[tid * 16 + 0] = c1; phi[tid * 16 + 8] = s1;
        float ck = c1, sk = s1;
#pragma unroll
        for (int h = 1; h < 8; ++h) {
            float cn = ck * c1 - sk * s1;
            float sn = sk * c1 + ck * s1;
            phi[tid * 16 + h] = cn; phi[tid * 16 + 8 + h] = sn;
            ck = cn; sk = sn;
        }
    }
    __syncthreads();
    int o = tid & 31, p = tid >> 5;
    float acc = 0.f;
    for (int k = p * 256; k < p * 256 + 256; ++k)
        acc = fmaf(phi[k], B[k * C_LAT + o], acc);
    part[p][o] = acc;
    __syncthreads();
    if (tid < 32) {
        float s = 0.f;
#pragma unroll
        for (int pp = 0; pp < 8; ++pp) s += part[pp][tid];
        if (is_f32) ((float*)out)[g * C_LAT + tid] = s;
        else        ((bf16*)out)[g * C_LAT + tid] = __float2bfloat16(s);
    }
}

extern "C" void kernel_launch(void* const* d_in, const int* in_sizes, int n_in,
                              void* d_out, int out_size, void* d_ws, size_t ws_size,
                              hipStream_t stream) {
    const void* features = d_in[0];
    const int*  edge     = (const int*)d_in[1];
    const int*  batch    = (const int*)d_in[2];
    const void* W_embed  = d_in[3];
    const void* W_mp     = d_in[4];
    const void* W_read   = d_in[5];

    const int N = in_sizes[0] / C_IN;
    const int E = in_sizes[1] / 2;
    const int* row = edge;
    const int* col = edge + E;
    const int nScanBlocks = (N + 1023) / 1024;

    char* ws = (char*)d_ws;
    auto alloc = [&](size_t bytes) { char* p = ws; ws += (bytes + 255) & ~(size_t)255; return p; };
    float* h_a    = (float*)alloc((size_t)N * C_HID * 4);
    float* h_b    = (float*)alloc((size_t)N * C_HID * 4);
    f16*   BteH   = (f16*)alloc((size_t)C_HID * 1024 * 2);
    f16*   BteL   = (f16*)alloc((size_t)C_HID * 1024 * 2);
    f16*   BtmpH  = (f16*)alloc((size_t)C_L * C_HID * 2048 * 2);
    f16*   BtmpL  = (f16*)alloc((size_t)C_L * C_HID * 2048 * 2);
    float* Brd    = (float*)alloc((size_t)2048 * C_LAT * 4);
    int*   deg    = (int*)alloc((size_t)N * 4);
    float* dinv   = (float*)alloc((size_t)N * 4);
    int*   rowptr = (int*)alloc((size_t)(N + 1) * 4);
    int*   cursor = (int*)alloc((size_t)N * 4);
    int*   srcs   = (int*)alloc((size_t)(E + N) * 4);
    int*   bsum   = (int*)alloc((size_t)nScanBlocks * 4);
    int*   gstart = (int*)alloc((size_t)(C_G + 1) * 4);
    int*   dflag  = (int*)alloc(256);

    hipMemsetAsync(deg, 0, (size_t)N * 4, stream);
    hipMemsetAsync(cursor, 0, (size_t)N * 4, stream);

    detect_dtype<<<1, 256, 0, stream>>>((const unsigned short*)W_embed, dflag);

    repack_embed<<<(2 * C_HID * C_IN * C_H + 255) / 256, 256, 0, stream>>>(W_embed, BteH, BteL, dflag);
    repack_mp<<<(C_L * 2 * C_HID * C_HID * C_H + 255) / 256, 256, 0, stream>>>(W_mp, BtmpH, BtmpL, dflag);
    repack_read<<<(2 * C_LAT * C_HID * C_H + 255) / 256, 256, 0, stream>>>(W_read, Brd, dflag);

    deg_count<<<(E + N + 255) / 256, 256, 0, stream>>>(col, deg, E, N);
    dinv_kernel<<<(N + 255) / 256, 256, 0, stream>>>(deg, dinv, N);
    graph_bounds<<<1, 128, 0, stream>>>(batch, gstart, N);
    scan1<<<nScanBlocks, 1024, 0, stream>>>(deg, rowptr, bsum, N);
    scan2<<<1, 64, 0, stream>>>(bsum, nScanBlocks);
    scan3<<<nScanBlocks, 1024, 0, stream>>>(rowptr, bsum, N);
    csr_fill<<<(E + N + 255) / 256, 256, 0, stream>>>(row, col, rowptr, cursor, srcs, E, N);

    const int gemm_grid = (N + 63) / 64;
    kan_gemm_mfma<C_IN><<<gemm_grid, 256, 0, stream>>>(features, BteH, BteL, h_a, N, dflag);
    for (int l = 0; l < C_L; ++l) {
        kan_gemm_mfma<C_HID><<<gemm_grid, 256, 0, stream>>>(h_a, BtmpH + (size_t)l * C_HID * 2048,
                                                            BtmpL + (size_t)l * C_HID * 2048, h_b, N, nullptr);
        aggregate<<<((size_t)N * 64 + 255) / 256, 256, 0, stream>>>(h_b, h_a, rowptr, srcs, dinv, N);
    }

    pool_readout<<<C_G, 256, 0, stream>>>(h_a, gstart, Brd, d_out, dflag);
}

// Round 6
// 1253.716 us; speedup vs baseline: 2.0180x; 1.0101x over previous
//
#include <hip/hip_runtime.h>
#include <hip/hip_bf16.h>
#include <cstdint>

typedef __hip_bfloat16 bf16;
typedef _Float16 f16;
typedef f16 f16x2 __attribute__((ext_vector_type(2)));
typedef f16 f16x8 __attribute__((ext_vector_type(8)));
typedef float f32x4 __attribute__((ext_vector_type(4)));

#define C_IN   64
#define C_HID  128
#define C_LAT  32
#define C_H    8
#define C_L    3
#define C_G    64

// Runtime input-dtype handling (harness may hand fp32 or bf16). flag==1 -> fp32.
__device__ inline float load_in(const void* p, size_t idx, int is_f32) {
    if (is_f32) return ((const float*)p)[idx];
    return __bfloat162float(((const bf16*)p)[idx]);
}

__global__ void detect_dtype(const unsigned short* __restrict__ W, int* __restrict__ flag) {
    __shared__ int cnt;
    if (threadIdx.x == 0) cnt = 0;
    __syncthreads();
    int local = 0;
    for (int i = threadIdx.x; i < 8192; i += 256) {
        int e = (W[i] >> 7) & 0xFF;
        if (e >= 135) local++;
    }
    atomicAdd(&cnt, local);
    __syncthreads();
    if (threadIdx.x == 0) *flag = (cnt > 64) ? 1 : 0;
}

// ---------- weight repack -> split fp16 (hi/lo) Bt[n][k], k = i*16 + trig*8 + h ----------
__device__ inline void split16(float v, f16& hi, f16& lo) {
    hi = (f16)v;
    lo = (f16)(v - (float)hi);
}

__global__ void repack_embed(const void* __restrict__ W, f16* __restrict__ Bh, f16* __restrict__ Bl,
                             const int* __restrict__ flagp) {
    const int is_f32 = *flagp;
    int idx = blockIdx.x * blockDim.x + threadIdx.x;
    if (idx >= 2 * C_HID * C_IN * C_H) return;
    int h = idx & 7; int t = idx >> 3;
    int i = t & 63; t >>= 6;
    int o = t & 127; int trig = t >> 7;
    f16 hi, lo; split16(load_in(W, idx, is_f32), hi, lo);
    int k = i * 16 + trig * 8 + h;
    Bh[o * 1024 + k] = hi;
    Bl[o * 1024 + k] = lo;
}

__global__ void repack_mp(const void* __restrict__ W, f16* __restrict__ Bh, f16* __restrict__ Bl,
                          const int* __restrict__ flagp) {
    const int is_f32 = *flagp;
    int idx = blockIdx.x * blockDim.x + threadIdx.x;
    if (idx >= C_L * 2 * C_HID * C_HID * C_H) return;
    int h = idx & 7; int t = idx >> 3;
    int i = t & 127; t >>= 7;
    int o = t & 127; t >>= 7;
    int trig = t & 1; int l = t >> 1;
    f16 hi, lo; split16(load_in(W, idx, is_f32), hi, lo);
    size_t k = (size_t)(l * 128 + o) * 2048 + i * 16 + trig * 8 + h;
    Bh[k] = hi;
    Bl[k] = lo;
}

// readout weights stay fp32 (tiny GEMM)
__global__ void repack_read(const void* __restrict__ W, float* __restrict__ B, const int* __restrict__ flagp) {
    const int is_f32 = *flagp;
    int idx = blockIdx.x * blockDim.x + threadIdx.x;
    if (idx >= 2 * C_LAT * C_HID * C_H) return;
    int h = idx & 7; int t = idx >> 3;
    int i = t & 127; t >>= 7;
    int o = t & 31; int trig = t >> 5;
    B[(i * 16 + trig * 8 + h) * C_LAT + o] = load_in(W, idx, is_f32);
}

// ---------- graph prep ----------
__global__ void deg_count(const int* __restrict__ col, int* __restrict__ deg, int E, int N) {
    int idx = blockIdx.x * blockDim.x + threadIdx.x;
    if (idx >= E + N) return;
    int c = (idx < E) ? col[idx] : (idx - E);
    atomicAdd(&deg[c], 1);
}

__global__ void dinv_kernel(const int* __restrict__ deg, float* __restrict__ dinv, int N) {
    int n = blockIdx.x * blockDim.x + threadIdx.x;
    if (n >= N) return;
    dinv[n] = rsqrtf((float)deg[n]);   // deg >= 1 (self loop)
}

// batch is sorted: gstart[g] = lower_bound(batch, g), g = 0..G (gstart[G] = N)
__global__ void graph_bounds(const int* __restrict__ batch, int* __restrict__ gstart, int N) {
    int g = threadIdx.x;
    if (g > C_G) return;
    int lo = 0, hi = N;
    while (lo < hi) {
        int mid = (lo + hi) >> 1;
        if (batch[mid] < g) lo = mid + 1; else hi = mid;
    }
    gstart[g] = lo;
}

// ---------- hierarchical exclusive scan of deg -> rowptr ----------
__global__ void scan1(const int* __restrict__ deg, int* __restrict__ rowptr,
                      int* __restrict__ bsum, int N) {
    __shared__ int sdata[1024];
    int i = blockIdx.x * 1024 + threadIdx.x;
    int v = (i < N) ? deg[i] : 0;
    sdata[threadIdx.x] = v;
    __syncthreads();
    for (int off = 1; off < 1024; off <<= 1) {
        int t = (threadIdx.x >= (unsigned)off) ? sdata[threadIdx.x - off] : 0;
        __syncthreads();
        sdata[threadIdx.x] += t;
        __syncthreads();
    }
    if (i < N) rowptr[i + 1] = sdata[threadIdx.x];
    if (threadIdx.x == 1023) bsum[blockIdx.x] = sdata[1023];
}

__global__ void scan2(int* __restrict__ bsum, int nb) {
    if (threadIdx.x == 0) {
        int acc = 0;
        for (int i = 0; i < nb; ++i) { int t = bsum[i]; bsum[i] = acc; acc += t; }
    }
}

__global__ void scan3(int* __restrict__ rowptr, const int* __restrict__ bsum, int N) {
    int i = blockIdx.x * 1024 + threadIdx.x;
    if (i < N) rowptr[i + 1] += bsum[blockIdx.x];
    if (i == 0) rowptr[0] = 0;
}

__global__ void csr_fill(const int* __restrict__ row, const int* __restrict__ col,
                         const int* __restrict__ rowptr, int* __restrict__ cursor,
                         int* __restrict__ srcs, int E, int N) {
    int idx = blockIdx.x * blockDim.x + threadIdx.x;
    if (idx >= E + N) return;
    int r, c;
    if (idx < E) { r = row[idx]; c = col[idx]; } else { r = c = idx - E; }
    int pos = rowptr[c] + atomicAdd(&cursor[c], 1);
    srcs[pos] = r;
}

// ---------- Phi split-fp16 generation: 16 values (cos(kx) k=1..8, sin(kx) k=1..8) ----------
#define SR 40   // LDS row stride in f16 (32 data + 8 pad); 80 B: 16B-aligned, non-pow2 banks

__device__ inline void phi_write_split(f16* __restrict__ Ah, f16* __restrict__ Al,
                                       int row, int f, float x) {
    float c[8], s[8];
    __sincosf(x, &s[0], &c[0]);
#pragma unroll
    for (int h = 1; h < 8; ++h) {
        c[h] = c[h-1] * c[0] - s[h-1] * s[0];
        s[h] = s[h-1] * c[0] + c[h-1] * s[0];
    }
    f16x8 ch, cl, sh, sl;
#pragma unroll
    for (int h = 0; h < 8; ++h) {
        f16 hi, lo;
        split16(c[h], hi, lo); ch[h] = hi; cl[h] = lo;
        split16(s[h], hi, lo); sh[h] = hi; sl[h] = lo;
    }
    *(f16x8*)&Ah[row * SR + f * 16]     = ch;
    *(f16x8*)&Ah[row * SR + f * 16 + 8] = sh;
    *(f16x8*)&Al[row * SR + f * 16]     = cl;
    *(f16x8*)&Al[row * SR + f * 16 + 8] = sl;
}

// ---------- split-fp16 MFMA fused-Phi GEMM: Y[M,128] = Phi(X)[M, INF*16] x Bt^T ----------
// Block: 64 M-rows x 128 N-cols, 4 waves side by side (wave tile 64x32, acc 4x2).
// K chunked by 32 (2 input features). acc = Ah*Bh + Ah*Bl + Al*Bh (fp32-accurate).
// F16OUT: store fp16 h pre-scaled by dinv[row] (consumed by the gather in aggregate).
template<int INF, bool F16OUT>
__global__ __launch_bounds__(256, 3) void kan_gemm_mfma(const void* __restrict__ X,
                                                        const f16* __restrict__ Bth, const f16* __restrict__ Btl,
                                                        float* __restrict__ Yf, f16* __restrict__ Yh,
                                                        const float* __restrict__ dinv,
                                                        int M, const int* __restrict__ flagp) {
    constexpr int K = INF * 16;
    constexpr int NCH = INF / 2;     // chunks of K=32
    __shared__ f16 Ah[64 * SR], Al[64 * SR], Bh[128 * SR], Bl[128 * SR];
    __shared__ float dinvs[64];
    const int is_f32 = flagp ? *flagp : 1;
    const int tid  = threadIdx.x;
    const int m0   = blockIdx.x * 64;
    const int w    = tid >> 6, lane = tid & 63;
    const int quad = lane >> 4, l16 = lane & 15;

    const int prow = tid & 63;
    const int pf   = (tid >> 6) & 1;
    const bool pact = tid < 128;
    const int gm   = m0 + prow;
    const int br = tid >> 1, bhs = tid & 1;

    if (F16OUT && tid < 64) dinvs[tid] = (m0 + tid < M) ? dinv[m0 + tid] : 0.f;

    f32x4 acc[4][2] = {};

    float xv = 0.f;
    if (pact && gm < M) xv = load_in(X, (size_t)gm * INF + pf, is_f32);

    for (int c = 0; c < NCH; ++c) {
        float xn = 0.f;
        if (c + 1 < NCH && pact && gm < M)
            xn = load_in(X, (size_t)gm * INF + (c + 1) * 2 + pf, is_f32);

        const f16* gbh = Bth + (size_t)br * K + c * 32 + bhs * 16;
        const f16* gbl = Btl + (size_t)br * K + c * 32 + bhs * 16;
        f16x8 b0 = ((const f16x8*)gbh)[0];
        f16x8 b1 = ((const f16x8*)gbh)[1];
        f16x8 b2 = ((const f16x8*)gbl)[0];
        f16x8 b3 = ((const f16x8*)gbl)[1];

        if (pact) phi_write_split(Ah, Al, prow, pf, xv);

        f16* dh = &Bh[br * SR + bhs * 16];
        f16* dl = &Bl[br * SR + bhs * 16];
        ((f16x8*)dh)[0] = b0; ((f16x8*)dh)[1] = b1;
        ((f16x8*)dl)[0] = b2; ((f16x8*)dl)[1] = b3;
        __syncthreads();

        f16x8 ah[4], al[4], bhf[2], blf[2];
#pragma unroll
        for (int mt = 0; mt < 4; ++mt) {
            ah[mt] = *(const f16x8*)&Ah[(mt * 16 + l16) * SR + quad * 8];
            al[mt] = *(const f16x8*)&Al[(mt * 16 + l16) * SR + quad * 8];
        }
#pragma unroll
        for (int nt = 0; nt < 2; ++nt) {
            bhf[nt] = *(const f16x8*)&Bh[(w * 32 + nt * 16 + l16) * SR + quad * 8];
            blf[nt] = *(const f16x8*)&Bl[(w * 32 + nt * 16 + l16) * SR + quad * 8];
        }
#pragma unroll
        for (int mt = 0; mt < 4; ++mt)
#pragma unroll
            for (int nt = 0; nt < 2; ++nt) {
                acc[mt][nt] = __builtin_amdgcn_mfma_f32_16x16x32_f16(ah[mt], bhf[nt], acc[mt][nt], 0, 0, 0);
                acc[mt][nt] = __builtin_amdgcn_mfma_f32_16x16x32_f16(ah[mt], blf[nt], acc[mt][nt], 0, 0, 0);
                acc[mt][nt] = __builtin_amdgcn_mfma_f32_16x16x32_f16(al[mt], bhf[nt], acc[mt][nt], 0, 0, 0);
            }
        __syncthreads();
        xv = xn;
    }

    // C/D layout: col = lane&15, row = quad*4 + reg
#pragma unroll
    for (int mt = 0; mt < 4; ++mt) {
        int rloc = mt * 16 + quad * 4;
#pragma unroll
        for (int nt = 0; nt < 2; ++nt) {
            int cn = w * 32 + nt * 16 + l16;
#pragma unroll
            for (int r = 0; r < 4; ++r) {
                int m = m0 + rloc + r;
                if (m < M) {
                    if (F16OUT) Yh[(size_t)m * 128 + cn] = (f16)(acc[mt][nt][r] * dinvs[rloc + r]);
                    else        Yf[(size_t)m * 128 + cn] = acc[mt][nt][r];
                }
            }
        }
    }
}

// ---------- CSR aggregation: one wave per dest; gather fp16 (dinv[src] pre-folded) ----------
__global__ void aggregate(const f16* __restrict__ Hin, float* __restrict__ Hout,
                          const int* __restrict__ rowptr, const int* __restrict__ srcs,
                          const float* __restrict__ dinv, int N) {
    int wave = (int)((blockIdx.x * blockDim.x + threadIdx.x) >> 6);
    int lane = threadIdx.x & 63;
    if (wave >= N) return;
    const f16x2* H2 = (const f16x2*)Hin;
    int beg = rowptr[wave], end = rowptr[wave + 1];
    float2 acc = {0.f, 0.f};
    for (int j = beg; j < end; ++j) {
        int s = srcs[j];
        f16x2 hv = H2[(size_t)s * 64 + lane];
        acc.x += (float)hv[0];
        acc.y += (float)hv[1];
    }
    float dv = dinv[wave];
    acc.x *= dv; acc.y *= dv;
    ((float2*)Hout)[(size_t)wave * 64 + lane] = acc;
}

// ---------- fused mean-pool + readout: block g sums rows [gstart[g], gstart[g+1]) ----------
__global__ __launch_bounds__(256) void pool_readout(const float* __restrict__ H, const int* __restrict__ gstart,
                                                    const float* __restrict__ B, void* __restrict__ out,
                                                    const int* __restrict__ flagp) {
    __shared__ float phi[2048];
    __shared__ float red[256];
    __shared__ float part[8][32];
    const int is_f32 = *flagp;
    int g = blockIdx.x;
    int tid = threadIdx.x;
    int s0 = gstart[g], e0 = gstart[g + 1];
    int f = tid & 127, half = tid >> 7;
    float sum = 0.f;
    for (int n = s0 + half; n < e0; n += 2)
        sum += H[(size_t)n * C_HID + f];
    red[tid] = sum;
    __syncthreads();
    if (tid < 128) {
        float cnt = fmaxf((float)(e0 - s0), 1.0f);
        float x = (red[tid] + red[tid + 128]) / cnt;
        float s1, c1;
        __sincosf(x, &s1, &c1);
        phi[tid * 16 + 0] = c1; phi[tid * 16 + 8] = s1;
        float ck = c1, sk = s1;
#pragma unroll
        for (int h = 1; h < 8; ++h) {
            float cn = ck * c1 - sk * s1;
            float sn = sk * c1 + ck * s1;
            phi[tid * 16 + h] = cn; phi[tid * 16 + 8 + h] = sn;
            ck = cn; sk = sn;
        }
    }
    __syncthreads();
    int o = tid & 31, p = tid >> 5;
    float acc = 0.f;
    for (int k = p * 256; k < p * 256 + 256; ++k)
        acc = fmaf(phi[k], B[k * C_LAT + o], acc);
    part[p][o] = acc;
    __syncthreads();
    if (tid < 32) {
        float s = 0.f;
#pragma unroll
        for (int pp = 0; pp < 8; ++pp) s += part[pp][tid];
        if (is_f32) ((float*)out)[g * C_LAT + tid] = s;
        else        ((bf16*)out)[g * C_LAT + tid] = __float2bfloat16(s);
    }
}

extern "C" void kernel_launch(void* const* d_in, const int* in_sizes, int n_in,
                              void* d_out, int out_size, void* d_ws, size_t ws_size,
                              hipStream_t stream) {
    const void* features = d_in[0];
    const int*  edge     = (const int*)d_in[1];
    const int*  batch    = (const int*)d_in[2];
    const void* W_embed  = d_in[3];
    const void* W_mp     = d_in[4];
    const void* W_read   = d_in[5];

    const int N = in_sizes[0] / C_IN;
    const int E = in_sizes[1] / 2;
    const int* row = edge;
    const int* col = edge + E;
    const int nScanBlocks = (N + 1023) / 1024;

    char* ws = (char*)d_ws;
    auto alloc = [&](size_t bytes) { char* p = ws; ws += (bytes + 255) & ~(size_t)255; return p; };
    float* h_a    = (float*)alloc((size_t)N * C_HID * 4);
    f16*   h16    = (f16*)alloc((size_t)N * C_HID * 2);
    f16*   BteH   = (f16*)alloc((size_t)C_HID * 1024 * 2);
    f16*   BteL   = (f16*)alloc((size_t)C_HID * 1024 * 2);
    f16*   BtmpH  = (f16*)alloc((size_t)C_L * C_HID * 2048 * 2);
    f16*   BtmpL  = (f16*)alloc((size_t)C_L * C_HID * 2048 * 2);
    float* Brd    = (float*)alloc((size_t)2048 * C_LAT * 4);
    int*   deg    = (int*)alloc((size_t)N * 4);
    float* dinv   = (float*)alloc((size_t)N * 4);
    int*   rowptr = (int*)alloc((size_t)(N + 1) * 4);
    int*   cursor = (int*)alloc((size_t)N * 4);
    int*   srcs   = (int*)alloc((size_t)(E + N) * 4);
    int*   bsum   = (int*)alloc((size_t)nScanBlocks * 4);
    int*   gstart = (int*)alloc((size_t)(C_G + 1) * 4);
    int*   dflag  = (int*)alloc(256);

    hipMemsetAsync(deg, 0, (size_t)N * 4, stream);
    hipMemsetAsync(cursor, 0, (size_t)N * 4, stream);

    detect_dtype<<<1, 256, 0, stream>>>((const unsigned short*)W_embed, dflag);

    repack_embed<<<(2 * C_HID * C_IN * C_H + 255) / 256, 256, 0, stream>>>(W_embed, BteH, BteL, dflag);
    repack_mp<<<(C_L * 2 * C_HID * C_HID * C_H + 255) / 256, 256, 0, stream>>>(W_mp, BtmpH, BtmpL, dflag);
    repack_read<<<(2 * C_LAT * C_HID * C_H + 255) / 256, 256, 0, stream>>>(W_read, Brd, dflag);

    deg_count<<<(E + N + 255) / 256, 256, 0, stream>>>(col, deg, E, N);
    dinv_kernel<<<(N + 255) / 256, 256, 0, stream>>>(deg, dinv, N);
    graph_bounds<<<1, 128, 0, stream>>>(batch, gstart, N);
    scan1<<<nScanBlocks, 1024, 0, stream>>>(deg, rowptr, bsum, N);
    scan2<<<1, 64, 0, stream>>>(bsum, nScanBlocks);
    scan3<<<nScanBlocks, 1024, 0, stream>>>(rowptr, bsum, N);
    csr_fill<<<(E + N + 255) / 256, 256, 0, stream>>>(row, col, rowptr, cursor, srcs, E, N);

    const int gemm_grid = (N + 63) / 64;
    kan_gemm_mfma<C_IN, false><<<gemm_grid, 256, 0, stream>>>(features, BteH, BteL, h_a, nullptr, nullptr, N, dflag);
    for (int l = 0; l < C_L; ++l) {
        kan_gemm_mfma<C_HID, true><<<gemm_grid, 256, 0, stream>>>(h_a, BtmpH + (size_t)l * C_HID * 2048,
                                                                  BtmpL + (size_t)l * C_HID * 2048,
                                                                  nullptr, h16, dinv, N, nullptr);
        aggregate<<<((size_t)N * 64 + 255) / 256, 256, 0, stream>>>(h16, h_a, rowptr, srcs, dinv, N);
    }

    pool_readout<<<C_G, 256, 0, stream>>>(h_a, gstart, Brd, d_out, dflag);
}

// Round 7
// 936.303 us; speedup vs baseline: 2.7022x; 1.3390x over previous
//
#include <hip/hip_runtime.h>
#include <hip/hip_bf16.h>
#include <cstdint>

typedef __hip_bfloat16 bf16;
typedef _Float16 f16;
typedef f16 f16x2 __attribute__((ext_vector_type(2)));
typedef f16 f16x8 __attribute__((ext_vector_type(8)));
typedef float f32x4 __attribute__((ext_vector_type(4)));

#define C_IN   64
#define C_HID  128
#define C_LAT  32
#define C_H    8
#define C_L    3
#define C_G    64

// Runtime input-dtype handling (harness may hand fp32 or bf16). flag==1 -> fp32.
__device__ inline float load_in(const void* p, size_t idx, int is_f32) {
    if (is_f32) return ((const float*)p)[idx];
    return __bfloat162float(((const bf16*)p)[idx]);
}

__global__ void detect_dtype(const unsigned short* __restrict__ W, int* __restrict__ flag) {
    __shared__ int cnt;
    if (threadIdx.x == 0) cnt = 0;
    __syncthreads();
    int local = 0;
    for (int i = threadIdx.x; i < 8192; i += 256) {
        int e = (W[i] >> 7) & 0xFF;
        if (e >= 135) local++;
    }
    atomicAdd(&cnt, local);
    __syncthreads();
    if (threadIdx.x == 0) *flag = (cnt > 64) ? 1 : 0;
}

// ---------- weight repack -> split fp16 (hi/lo) Bt[n][k], k = i*16 + trig*8 + h ----------
__device__ inline void split16(float v, f16& hi, f16& lo) {
    hi = (f16)v;
    lo = (f16)(v - (float)hi);
}

__global__ void repack_embed(const void* __restrict__ W, f16* __restrict__ Bh, f16* __restrict__ Bl,
                             const int* __restrict__ flagp) {
    const int is_f32 = *flagp;
    int idx = blockIdx.x * blockDim.x + threadIdx.x;
    if (idx >= 2 * C_HID * C_IN * C_H) return;
    int h = idx & 7; int t = idx >> 3;
    int i = t & 63; t >>= 6;
    int o = t & 127; int trig = t >> 7;
    f16 hi, lo; split16(load_in(W, idx, is_f32), hi, lo);
    int k = i * 16 + trig * 8 + h;
    Bh[o * 1024 + k] = hi;
    Bl[o * 1024 + k] = lo;
}

__global__ void repack_mp(const void* __restrict__ W, f16* __restrict__ Bh, f16* __restrict__ Bl,
                          const int* __restrict__ flagp) {
    const int is_f32 = *flagp;
    int idx = blockIdx.x * blockDim.x + threadIdx.x;
    if (idx >= C_L * 2 * C_HID * C_HID * C_H) return;
    int h = idx & 7; int t = idx >> 3;
    int i = t & 127; t >>= 7;
    int o = t & 127; t >>= 7;
    int trig = t & 1; int l = t >> 1;
    f16 hi, lo; split16(load_in(W, idx, is_f32), hi, lo);
    size_t k = (size_t)(l * 128 + o) * 2048 + i * 16 + trig * 8 + h;
    Bh[k] = hi;
    Bl[k] = lo;
}

// readout weights stay fp32 (tiny GEMM)
__global__ void repack_read(const void* __restrict__ W, float* __restrict__ B, const int* __restrict__ flagp) {
    const int is_f32 = *flagp;
    int idx = blockIdx.x * blockDim.x + threadIdx.x;
    if (idx >= 2 * C_LAT * C_HID * C_H) return;
    int h = idx & 7; int t = idx >> 3;
    int i = t & 127; t >>= 7;
    int o = t & 31; int trig = t >> 5;
    B[(i * 16 + trig * 8 + h) * C_LAT + o] = load_in(W, idx, is_f32);
}

// ---------- graph prep ----------
__global__ void deg_count(const int* __restrict__ col, int* __restrict__ deg, int E, int N) {
    int idx = blockIdx.x * blockDim.x + threadIdx.x;
    if (idx >= E + N) return;
    int c = (idx < E) ? col[idx] : (idx - E);
    atomicAdd(&deg[c], 1);
}

__global__ void dinv_kernel(const int* __restrict__ deg, float* __restrict__ dinv, int N) {
    int n = blockIdx.x * blockDim.x + threadIdx.x;
    if (n >= N) return;
    dinv[n] = rsqrtf((float)deg[n]);   // deg >= 1 (self loop)
}

// batch is sorted: gstart[g] = lower_bound(batch, g), g = 0..G (gstart[G] = N)
__global__ void graph_bounds(const int* __restrict__ batch, int* __restrict__ gstart, int N) {
    int g = threadIdx.x;
    if (g > C_G) return;
    int lo = 0, hi = N;
    while (lo < hi) {
        int mid = (lo + hi) >> 1;
        if (batch[mid] < g) lo = mid + 1; else hi = mid;
    }
    gstart[g] = lo;
}

// ---------- hierarchical exclusive scan of deg -> rowptr ----------
__global__ void scan1(const int* __restrict__ deg, int* __restrict__ rowptr,
                      int* __restrict__ bsum, int N) {
    __shared__ int sdata[1024];
    int i = blockIdx.x * 1024 + threadIdx.x;
    int v = (i < N) ? deg[i] : 0;
    sdata[threadIdx.x] = v;
    __syncthreads();
    for (int off = 1; off < 1024; off <<= 1) {
        int t = (threadIdx.x >= (unsigned)off) ? sdata[threadIdx.x - off] : 0;
        __syncthreads();
        sdata[threadIdx.x] += t;
        __syncthreads();
    }
    if (i < N) rowptr[i + 1] = sdata[threadIdx.x];
    if (threadIdx.x == 1023) bsum[blockIdx.x] = sdata[1023];
}

__global__ void scan2(int* __restrict__ bsum, int nb) {
    if (threadIdx.x == 0) {
        int acc = 0;
        for (int i = 0; i < nb; ++i) { int t = bsum[i]; bsum[i] = acc; acc += t; }
    }
}

__global__ void scan3(int* __restrict__ rowptr, const int* __restrict__ bsum, int N) {
    int i = blockIdx.x * 1024 + threadIdx.x;
    if (i < N) rowptr[i + 1] += bsum[blockIdx.x];
    if (i == 0) rowptr[0] = 0;
}

__global__ void csr_fill(const int* __restrict__ row, const int* __restrict__ col,
                         const int* __restrict__ rowptr, int* __restrict__ cursor,
                         int* __restrict__ srcs, int E, int N) {
    int idx = blockIdx.x * blockDim.x + threadIdx.x;
    if (idx >= E + N) return;
    int r, c;
    if (idx < E) { r = row[idx]; c = col[idx]; } else { r = c = idx - E; }
    int pos = rowptr[c] + atomicAdd(&cursor[c], 1);
    srcs[pos] = r;
}

// ---------- Phi split-fp16 generation: 16 values (cos(kx) k=1..8, sin(kx) k=1..8) ----------
#define SR 40   // LDS row stride in f16 (32 data + 8 pad); 80 B: 16B-aligned, non-pow2 banks

__device__ inline void phi_write_split(f16* __restrict__ Ah, f16* __restrict__ Al,
                                       int row, int f, float x) {
    float c[8], s[8];
    __sincosf(x, &s[0], &c[0]);
#pragma unroll
    for (int h = 1; h < 8; ++h) {
        c[h] = c[h-1] * c[0] - s[h-1] * s[0];
        s[h] = s[h-1] * c[0] + c[h-1] * s[0];
    }
    f16x8 ch, cl, sh, sl;
#pragma unroll
    for (int h = 0; h < 8; ++h) {
        f16 hi, lo;
        split16(c[h], hi, lo); ch[h] = hi; cl[h] = lo;
        split16(s[h], hi, lo); sh[h] = hi; sl[h] = lo;
    }
    *(f16x8*)&Ah[row * SR + f * 16]     = ch;
    *(f16x8*)&Ah[row * SR + f * 16 + 8] = sh;
    *(f16x8*)&Al[row * SR + f * 16]     = cl;
    *(f16x8*)&Al[row * SR + f * 16 + 8] = sl;
}

// ---------- split-fp16 MFMA fused-Phi GEMM: Y[M,128] = Phi(X)[M, INF*16] x Bt^T ----------
template<int INF, bool F16OUT>
__global__ __launch_bounds__(256, 3) void kan_gemm_mfma(const void* __restrict__ X,
                                                        const f16* __restrict__ Bth, const f16* __restrict__ Btl,
                                                        float* __restrict__ Yf, f16* __restrict__ Yh,
                                                        const float* __restrict__ dinv,
                                                        int M, const int* __restrict__ flagp) {
    constexpr int K = INF * 16;
    constexpr int NCH = INF / 2;     // chunks of K=32
    __shared__ f16 Ah[64 * SR], Al[64 * SR], Bh[128 * SR], Bl[128 * SR];
    __shared__ float dinvs[64];
    const int is_f32 = flagp ? *flagp : 1;
    const int tid  = threadIdx.x;
    const int m0   = blockIdx.x * 64;
    const int w    = tid >> 6, lane = tid & 63;
    const int quad = lane >> 4, l16 = lane & 15;

    const int prow = tid & 63;
    const int pf   = (tid >> 6) & 1;
    const bool pact = tid < 128;
    const int gm   = m0 + prow;
    const int br = tid >> 1, bhs = tid & 1;

    if (F16OUT && tid < 64) dinvs[tid] = (m0 + tid < M) ? dinv[m0 + tid] : 0.f;

    f32x4 acc[4][2] = {};

    float xv = 0.f;
    if (pact && gm < M) xv = load_in(X, (size_t)gm * INF + pf, is_f32);

    for (int c = 0; c < NCH; ++c) {
        float xn = 0.f;
        if (c + 1 < NCH && pact && gm < M)
            xn = load_in(X, (size_t)gm * INF + (c + 1) * 2 + pf, is_f32);

        const f16* gbh = Bth + (size_t)br * K + c * 32 + bhs * 16;
        const f16* gbl = Btl + (size_t)br * K + c * 32 + bhs * 16;
        f16x8 b0 = ((const f16x8*)gbh)[0];
        f16x8 b1 = ((const f16x8*)gbh)[1];
        f16x8 b2 = ((const f16x8*)gbl)[0];
        f16x8 b3 = ((const f16x8*)gbl)[1];

        if (pact) phi_write_split(Ah, Al, prow, pf, xv);

        f16* dh = &Bh[br * SR + bhs * 16];
        f16* dl = &Bl[br * SR + bhs * 16];
        ((f16x8*)dh)[0] = b0; ((f16x8*)dh)[1] = b1;
        ((f16x8*)dl)[0] = b2; ((f16x8*)dl)[1] = b3;
        __syncthreads();

        f16x8 ah[4], al[4], bhf[2], blf[2];
#pragma unroll
        for (int mt = 0; mt < 4; ++mt) {
            ah[mt] = *(const f16x8*)&Ah[(mt * 16 + l16) * SR + quad * 8];
            al[mt] = *(const f16x8*)&Al[(mt * 16 + l16) * SR + quad * 8];
        }
#pragma unroll
        for (int nt = 0; nt < 2; ++nt) {
            bhf[nt] = *(const f16x8*)&Bh[(w * 32 + nt * 16 + l16) * SR + quad * 8];
            blf[nt] = *(const f16x8*)&Bl[(w * 32 + nt * 16 + l16) * SR + quad * 8];
        }
#pragma unroll
        for (int mt = 0; mt < 4; ++mt)
#pragma unroll
            for (int nt = 0; nt < 2; ++nt) {
                acc[mt][nt] = __builtin_amdgcn_mfma_f32_16x16x32_f16(ah[mt], bhf[nt], acc[mt][nt], 0, 0, 0);
                acc[mt][nt] = __builtin_amdgcn_mfma_f32_16x16x32_f16(ah[mt], blf[nt], acc[mt][nt], 0, 0, 0);
                acc[mt][nt] = __builtin_amdgcn_mfma_f32_16x16x32_f16(al[mt], bhf[nt], acc[mt][nt], 0, 0, 0);
            }
        __syncthreads();
        xv = xn;
    }

    // C/D layout: col = lane&15, row = quad*4 + reg
#pragma unroll
    for (int mt = 0; mt < 4; ++mt) {
        int rloc = mt * 16 + quad * 4;
#pragma unroll
        for (int nt = 0; nt < 2; ++nt) {
            int cn = w * 32 + nt * 16 + l16;
#pragma unroll
            for (int r = 0; r < 4; ++r) {
                int m = m0 + rloc + r;
                if (m < M) {
                    if (F16OUT) Yh[(size_t)m * 128 + cn] = (f16)(acc[mt][nt][r] * dinvs[rloc + r]);
                    else        Yf[(size_t)m * 128 + cn] = acc[mt][nt][r];
                }
            }
        }
    }
}

// ---------- CSR aggregation v2: one wave per dest, shuffled src staging + 4-deep gather ----------
__global__ __launch_bounds__(256) void aggregate(const f16* __restrict__ Hin, float* __restrict__ Hout,
                                                 const int* __restrict__ rowptr, const int* __restrict__ srcs,
                                                 const float* __restrict__ dinv, int N) {
    int wave = (int)((blockIdx.x * blockDim.x + threadIdx.x) >> 6);
    int lane = threadIdx.x & 63;
    if (wave >= N) return;
    const f16x2* H2 = (const f16x2*)Hin;
    int beg = rowptr[wave], end = rowptr[wave + 1];
    float2 a0 = {0.f, 0.f}, a1 = {0.f, 0.f};
    int j = beg;
    while (j < end) {
        int cnt = end - j; if (cnt > 64) cnt = 64;
        // one coalesced load stages up to 64 edge IDs across the wave
        int sv = (lane < cnt) ? srcs[j + lane] : 0;
        int t = 0;
        for (; t + 4 <= cnt; t += 4) {
            int s0 = __shfl(sv, t + 0);
            int s1 = __shfl(sv, t + 1);
            int s2 = __shfl(sv, t + 2);
            int s3 = __shfl(sv, t + 3);
            // 4 independent row-gathers in flight
            f16x2 h0 = H2[(size_t)s0 * 64 + lane];
            f16x2 h1 = H2[(size_t)s1 * 64 + lane];
            f16x2 h2 = H2[(size_t)s2 * 64 + lane];
            f16x2 h3 = H2[(size_t)s3 * 64 + lane];
            a0.x += (float)h0[0] + (float)h1[0];
            a0.y += (float)h0[1] + (float)h1[1];
            a1.x += (float)h2[0] + (float)h3[0];
            a1.y += (float)h2[1] + (float)h3[1];
        }
        for (; t < cnt; ++t) {
            int s0 = __shfl(sv, t);
            f16x2 h0 = H2[(size_t)s0 * 64 + lane];
            a0.x += (float)h0[0];
            a0.y += (float)h0[1];
        }
        j += cnt;
    }
    float dv = dinv[wave];
    float2 acc = {(a0.x + a1.x) * dv, (a0.y + a1.y) * dv};
    ((float2*)Hout)[(size_t)wave * 64 + lane] = acc;
}

// ---------- fused mean-pool + readout: block g sums rows [gstart[g], gstart[g+1]) ----------
__global__ __launch_bounds__(256) void pool_readout(const float* __restrict__ H, const int* __restrict__ gstart,
                                                    const float* __restrict__ B, void* __restrict__ out,
                                                    const int* __restrict__ flagp) {
    __shared__ float phi[2048];
    __shared__ float red[256];
    __shared__ float part[8][32];
    const int is_f32 = *flagp;
    int g = blockIdx.x;
    int tid = threadIdx.x;
    int s0 = gstart[g], e0 = gstart[g + 1];
    int f = tid & 127, half = tid >> 7;
    float sum = 0.f;
    for (int n = s0 + half; n < e0; n += 2)
        sum += H[(size_t)n * C_HID + f];
    red[tid] = sum;
    __syncthreads();
    if (tid < 128) {
        float cnt = fmaxf((float)(e0 - s0), 1.0f);
        float x = (red[tid] + red[tid + 128]) / cnt;
        float s1, c1;
        __sincosf(x, &s1, &c1);
        phi[tid * 16 + 0] = c1; phi[tid * 16 + 8] = s1;
        float ck = c1, sk = s1;
#pragma unroll
        for (int h = 1; h < 8; ++h) {
            float cn = ck * c1 - sk * s1;
            float sn = sk * c1 + ck * s1;
            phi[tid * 16 + h] = cn; phi[tid * 16 + 8 + h] = sn;
            ck = cn; sk = sn;
        }
    }
    __syncthreads();
    int o = tid & 31, p = tid >> 5;
    float acc = 0.f;
    for (int k = p * 256; k < p * 256 + 256; ++k)
        acc = fmaf(phi[k], B[k * C_LAT + o], acc);
    part[p][o] = acc;
    __syncthreads();
    if (tid < 32) {
        float s = 0.f;
#pragma unroll
        for (int pp = 0; pp < 8; ++pp) s += part[pp][tid];
        if (is_f32) ((float*)out)[g * C_LAT + tid] = s;
        else        ((bf16*)out)[g * C_LAT + tid] = __float2bfloat16(s);
    }
}

extern "C" void kernel_launch(void* const* d_in, const int* in_sizes, int n_in,
                              void* d_out, int out_size, void* d_ws, size_t ws_size,
                              hipStream_t stream) {
    const void* features = d_in[0];
    const int*  edge     = (const int*)d_in[1];
    const int*  batch    = (const int*)d_in[2];
    const void* W_embed  = d_in[3];
    const void* W_mp     = d_in[4];
    const void* W_read   = d_in[5];

    const int N = in_sizes[0] / C_IN;
    const int E = in_sizes[1] / 2;
    const int* row = edge;
    const int* col = edge + E;
    const int nScanBlocks = (N + 1023) / 1024;

    char* ws = (char*)d_ws;
    auto alloc = [&](size_t bytes) { char* p = ws; ws += (bytes + 255) & ~(size_t)255; return p; };
    float* h_a    = (float*)alloc((size_t)N * C_HID * 4);
    f16*   h16    = (f16*)alloc((size_t)N * C_HID * 2);
    f16*   BteH   = (f16*)alloc((size_t)C_HID * 1024 * 2);
    f16*   BteL   = (f16*)alloc((size_t)C_HID * 1024 * 2);
    f16*   BtmpH  = (f16*)alloc((size_t)C_L * C_HID * 2048 * 2);
    f16*   BtmpL  = (f16*)alloc((size_t)C_L * C_HID * 2048 * 2);
    float* Brd    = (float*)alloc((size_t)2048 * C_LAT * 4);
    int*   deg    = (int*)alloc((size_t)N * 4);
    float* dinv   = (float*)alloc((size_t)N * 4);
    int*   rowptr = (int*)alloc((size_t)(N + 1) * 4);
    int*   cursor = (int*)alloc((size_t)N * 4);
    int*   srcs   = (int*)alloc((size_t)(E + N) * 4);
    int*   bsum   = (int*)alloc((size_t)nScanBlocks * 4);
    int*   gstart = (int*)alloc((size_t)(C_G + 1) * 4);
    int*   dflag  = (int*)alloc(256);

    hipMemsetAsync(deg, 0, (size_t)N * 4, stream);
    hipMemsetAsync(cursor, 0, (size_t)N * 4, stream);

    detect_dtype<<<1, 256, 0, stream>>>((const unsigned short*)W_embed, dflag);

    repack_embed<<<(2 * C_HID * C_IN * C_H + 255) / 256, 256, 0, stream>>>(W_embed, BteH, BteL, dflag);
    repack_mp<<<(C_L * 2 * C_HID * C_HID * C_H + 255) / 256, 256, 0, stream>>>(W_mp, BtmpH, BtmpL, dflag);
    repack_read<<<(2 * C_LAT * C_HID * C_H + 255) / 256, 256, 0, stream>>>(W_read, Brd, dflag);

    deg_count<<<(E + N + 255) / 256, 256, 0, stream>>>(col, deg, E, N);
    dinv_kernel<<<(N + 255) / 256, 256, 0, stream>>>(deg, dinv, N);
    graph_bounds<<<1, 128, 0, stream>>>(batch, gstart, N);
    scan1<<<nScanBlocks, 1024, 0, stream>>>(deg, rowptr, bsum, N);
    scan2<<<1, 64, 0, stream>>>(bsum, nScanBlocks);
    scan3<<<nScanBlocks, 1024, 0, stream>>>(rowptr, bsum, N);
    csr_fill<<<(E + N + 255) / 256, 256, 0, stream>>>(row, col, rowptr, cursor, srcs, E, N);

    const int gemm_grid = (N + 63) / 64;
    kan_gemm_mfma<C_IN, false><<<gemm_grid, 256, 0, stream>>>(features, BteH, BteL, h_a, nullptr, nullptr, N, dflag);
    for (int l = 0; l < C_L; ++l) {
        kan_gemm_mfma<C_HID, true><<<gemm_grid, 256, 0, stream>>>(h_a, BtmpH + (size_t)l * C_HID * 2048,
                                                                  BtmpL + (size_t)l * C_HID * 2048,
                                                                  nullptr, h16, dinv, N, nullptr);
        aggregate<<<((size_t)N * 64 + 255) / 256, 256, 0, stream>>>(h16, h_a, rowptr, srcs, dinv, N);
    }

    pool_readout<<<C_G, 256, 0, stream>>>(h_a, gstart, Brd, d_out, dflag);
}